// Round 15
// baseline (383.788 us; speedup 1.0000x reference)
//
#include <hip/hip_runtime.h>
#include <hip/hip_bf16.h>
#include <math.h>

// ZoeDepth attractor layer, fused, v3:
//   v2 + LDS bank-conflict fixes + occupancy bump.
//   - ws padded [128][76] (ml-stride 304 dwords = 16 mod 32 -> 2-way, free)
//   - h exchange in bf16, rows [134] (conv2 read bank = 3p+4mc -> 2-way, free)
//   - union LDS 53.2 KB -> 3 blocks/CU (was 75.8 KB -> 2)
// conv1: register-blocked 8m x 4p per thread, w1 bf16 [m][k], x f32 [k][p].

__device__ __forceinline__ unsigned short f2bf(float f) {
    unsigned int u = __float_as_uint(f);
    u += 0x7fffu + ((u >> 16) & 1u);    // round-to-nearest-even
    return (unsigned short)(u >> 16);
}

__device__ __forceinline__ unsigned int pack2bf(float lo, float hi) {
    return (unsigned int)f2bf(lo) | ((unsigned int)f2bf(hi) << 16);
}

__global__ __launch_bounds__(512, 6)
void zoe_attractor_fused3(const float* __restrict__ x,
                          const float* __restrict__ prev_bin,
                          const float* __restrict__ w1,
                          const float* __restrict__ b1,
                          const float* __restrict__ w2,
                          const float* __restrict__ b2,
                          float* __restrict__ out)
{
    __shared__ union {
        struct {
            float xs[64][132];            // [k][p] f32, 33792 B (row 132 dw)
            unsigned short ws[128][76];   // [m][k] bf16, 19456 B (row 38 dw)
        } c1;                             // 53248 B
        struct {
            unsigned short hs[128][134];  // [p][m] bf16, 34304 B (row 67 dw)
            float as[16][128];            // 8192 B
        } c2;                             // 42496 B
    } sm;

    const int tid = threadIdx.x;
    const int bid = blockIdx.x;
    const int b    = bid >> 7;            // batch
    const int hrow = bid & 127;           // output row

    const int wave = tid >> 6;
    const int lane = tid & 63;
    const int wm = wave >> 1;             // 0..3 : m-group of 32
    const int wp = wave & 1;              // 0..1 : p-half of 64
    const int ml = lane >> 4;             // 0..3 : m-sub of 8
    const int pl = lane & 15;             // 0..15: p-sub of 4
    const int m0 = wm * 32 + ml * 8;
    const int p0 = wp * 64 + pl * 4;

    float acc[8][4];
    #pragma unroll
    for (int i = 0; i < 8; ++i)
        #pragma unroll
        for (int j = 0; j < 4; ++j) acc[i][j] = 0.0f;

    const float* xb = x + (size_t)b * 256 * 16384 + hrow * 128;

    for (int t = 0; t < 4; ++t) {
        // ---- stage x chunk [64k][128p] f32, coalesced float4 ----
        #pragma unroll
        for (int pass = 0; pass < 4; ++pass) {
            const int i  = pass * 512 + tid;
            const int k  = i >> 5;
            const int p4 = (i & 31) << 2;
            const float4 v = *reinterpret_cast<const float4*>(
                xb + (size_t)(t * 64 + k) * 16384 + p4);
            *reinterpret_cast<float4*>(&sm.c1.xs[k][p4]) = v;
        }
        // ---- stage w1 chunk [128m][64k] -> bf16, coalesced ----
        #pragma unroll
        for (int pass = 0; pass < 4; ++pass) {
            const int i  = pass * 512 + tid;
            const int m  = i >> 4;
            const int c4 = (i & 15) << 2;
            const float4 v = *reinterpret_cast<const float4*>(
                w1 + (size_t)m * 256 + t * 64 + c4);
            uint2 dd;
            dd.x = pack2bf(v.x, v.y);
            dd.y = pack2bf(v.z, v.w);
            *reinterpret_cast<uint2*>(&sm.c1.ws[m][c4]) = dd;
        }
        __syncthreads();

        // ---- compute: 16 groups of 4 k ----
        for (int g = 0; g < 16; ++g) {
            uint2 wreg[8];
            #pragma unroll
            for (int mm = 0; mm < 8; ++mm)
                wreg[mm] = *reinterpret_cast<const uint2*>(&sm.c1.ws[m0 + mm][g * 4]);
            #pragma unroll
            for (int kk = 0; kk < 4; ++kk) {
                const float4 xv = *reinterpret_cast<const float4*>(
                    &sm.c1.xs[g * 4 + kk][p0]);
                #pragma unroll
                for (int mm = 0; mm < 8; ++mm) {
                    const unsigned int d = (kk < 2) ? wreg[mm].x : wreg[mm].y;
                    const float wv = (kk & 1)
                        ? __uint_as_float(d & 0xffff0000u)
                        : __uint_as_float(d << 16);
                    acc[mm][0] = fmaf(wv, xv.x, acc[mm][0]);
                    acc[mm][1] = fmaf(wv, xv.y, acc[mm][1]);
                    acc[mm][2] = fmaf(wv, xv.z, acc[mm][2]);
                    acc[mm][3] = fmaf(wv, xv.w, acc[mm][3]);
                }
            }
        }
        __syncthreads();
    }

    // ---- bias + ReLU, exchange h via LDS [p][m] bf16 (uint4 = 8 m) ----
    float b1v[8];
    #pragma unroll
    for (int mm = 0; mm < 8; ++mm) b1v[mm] = b1[m0 + mm];

    #pragma unroll
    for (int pp = 0; pp < 4; ++pp) {
        float hv[8];
        #pragma unroll
        for (int mm = 0; mm < 8; ++mm)
            hv[mm] = fmaxf(acc[mm][pp] + b1v[mm], 0.0f);
        uint4 packed;
        packed.x = pack2bf(hv[0], hv[1]);
        packed.y = pack2bf(hv[2], hv[3]);
        packed.z = pack2bf(hv[4], hv[5]);
        packed.w = pack2bf(hv[6], hv[7]);
        *reinterpret_cast<uint4*>(&sm.c2.hs[p0 + pp][m0]) = packed;
    }
    __syncthreads();

    // ---- conv2: each thread 1 pixel x 4 attractors; w2 scalar (sL1-hot) ----
    const int p  = tid & 127;
    const int ag = tid >> 7;              // 0..3, uniform per 2-wave group
    float a[4] = {0.0f, 0.0f, 0.0f, 0.0f};
    #pragma unroll 4
    for (int mc = 0; mc < 16; ++mc) {
        const uint4 hp = *reinterpret_cast<const uint4*>(&sm.c2.hs[p][mc * 8]);
        float hv[8];
        hv[0] = __uint_as_float(hp.x << 16);
        hv[1] = __uint_as_float(hp.x & 0xffff0000u);
        hv[2] = __uint_as_float(hp.y << 16);
        hv[3] = __uint_as_float(hp.y & 0xffff0000u);
        hv[4] = __uint_as_float(hp.z << 16);
        hv[5] = __uint_as_float(hp.z & 0xffff0000u);
        hv[6] = __uint_as_float(hp.w << 16);
        hv[7] = __uint_as_float(hp.w & 0xffff0000u);
        #pragma unroll
        for (int aa = 0; aa < 4; ++aa) {
            const float* wr = w2 + (size_t)(ag * 4 + aa) * 128 + mc * 8; // uniform
            #pragma unroll
            for (int mm = 0; mm < 8; ++mm)
                a[aa] = fmaf(wr[mm], hv[mm], a[aa]);
        }
    }
    #pragma unroll
    for (int aa = 0; aa < 4; ++aa) {
        const int att = ag * 4 + aa;
        const float s = a[aa] + b2[att];
        sm.c2.as[att][p] = fmaxf(s, 0.0f) + log1pf(expf(-fabsf(s)));
    }
    __syncthreads();

    // ---- bilinear bin centers + attractor shifts + store (twice) ----
    const float scale = 63.0f / 127.0f;
    const float ysf = (float)hrow * scale;
    const int   y0  = (int)ysf;
    const float wy  = ysf - (float)y0;
    const int   y1  = (y0 + 1 < 63) ? (y0 + 1) : 63;
    const float omwy = 1.0f - wy;

    const float xf = (float)p * scale;
    const int   x0 = (int)xf;
    const float wx = xf - (float)x0;
    const int   x1 = (x0 + 1 < 63) ? (x0 + 1) : 63;
    const float omwx = 1.0f - wx;

    const float* pvb = prev_bin + (size_t)b * 64 * 4096;
    float* ob = out + (size_t)b * 64 * 16384 + hrow * 128;
    const size_t out2_off = (size_t)8 * 64 * 16384;

    #pragma unroll 4
    for (int jj = 0; jj < 16; ++jj) {
        const int j = ag + jj * 4;
        const float* pv = pvb + (size_t)j * 4096;
        const float v00 = pv[y0 * 64 + x0];
        const float v01 = pv[y1 * 64 + x0];
        const float v10 = pv[y0 * 64 + x1];
        const float v11 = pv[y1 * 64 + x1];
        const float t0 = v00 * omwy + v01 * wy;
        const float t1 = v10 * omwy + v11 * wy;
        const float bc = t0 * omwx + t1 * wx;

        float delta = 0.0f;
        #pragma unroll
        for (int att = 0; att < 16; ++att) {
            const float dx  = sm.c2.as[att][p] - bc;
            const float den = fmaf(300.0f * dx, dx, 1.0f);
            delta += dx * __builtin_amdgcn_rcpf(den);
        }
        const float ov = bc + delta;
        const size_t oi = (size_t)j * 16384 + p;
        ob[oi] = ov;
        ob[oi + out2_off] = ov;
    }
}

extern "C" void kernel_launch(void* const* d_in, const int* in_sizes, int n_in,
                              void* d_out, int out_size, void* d_ws, size_t ws_size,
                              hipStream_t stream) {
    const float* x        = (const float*)d_in[0];
    const float* prev_bin = (const float*)d_in[1];
    const float* w1       = (const float*)d_in[2];
    const float* b1       = (const float*)d_in[3];
    const float* w2       = (const float*)d_in[4];
    const float* b2       = (const float*)d_in[5];
    float* out = (float*)d_out;

    dim3 grid(1024), block(512);
    hipLaunchKernelGGL(zoe_attractor_fused3, grid, block, 0, stream,
                       x, prev_bin, w1, b1, w2, b2, out);
}